// Round 21
// baseline (6272.729 us; speedup 1.0000x reference)
//
#include <hip/hip_runtime.h>

#define NP 262144
#define DI 128
#define KCL 512
#define NIT 10
#define NCH 1024      // chunks for the counting sort
#define CHS 256       // points per chunk (NCH*CHS == NP)

// Fast-math-immune fp32 NaN test.
__device__ __forceinline__ bool isnan_bits32(float x) {
  unsigned b = __float_as_uint(x);
  return (b & 0x7FFFFFFFu) > 0x7F800000u;
}

// numpy pairwise_sum of v[i]*v[i] for n=128 (numpy's 8-accumulator unrolled path).
__device__ __forceinline__ float np_pairwise128_sq(const float* v) {
  float r[8];
  #pragma unroll
  for (int j = 0; j < 8; ++j) r[j] = __fmul_rn(v[j], v[j]);
  #pragma unroll
  for (int t = 1; t < 16; ++t)
    #pragma unroll
    for (int j = 0; j < 8; ++j)
      r[j] = __fadd_rn(r[j], __fmul_rn(v[8 * t + j], v[8 * t + j]));
  float t01 = __fadd_rn(r[0], r[1]), t23 = __fadd_rn(r[2], r[3]);
  float t45 = __fadd_rn(r[4], r[5]), t67 = __fadd_rn(r[6], r[7]);
  return __fadd_rn(__fadd_rn(t01, t23), __fadd_rn(t45, t67));
}

// ---------------- init: C0 = X[:512]; cnorm[k] = np-pairwise of c*c ----------------
__global__ void k_init(const float* __restrict__ X, float* __restrict__ C,
                       float* __restrict__ cnorm) {
  int k = blockIdx.x, d = threadIdx.x;
  float v = X[(size_t)k * DI + d];
  C[(size_t)k * DI + d] = v;
  __shared__ float row[DI];
  row[d] = v;
  __syncthreads();
  if (d == 0) cnorm[k] = np_pairwise128_sq(row);
}

// ---------------- xnorm: once per run (X constant). Streaming 8-acc pairwise. ----------
__global__ void k_xnorm(const float* __restrict__ X, float* __restrict__ xnorm) {
  const int p = blockIdx.x * 256 + threadIdx.x;
  const float4* X4 = (const float4*)X + (size_t)p * 32;
  float r[8];
  {
    float4 q0 = X4[0], q1 = X4[1];
    r[0] = __fmul_rn(q0.x, q0.x); r[1] = __fmul_rn(q0.y, q0.y);
    r[2] = __fmul_rn(q0.z, q0.z); r[3] = __fmul_rn(q0.w, q0.w);
    r[4] = __fmul_rn(q1.x, q1.x); r[5] = __fmul_rn(q1.y, q1.y);
    r[6] = __fmul_rn(q1.z, q1.z); r[7] = __fmul_rn(q1.w, q1.w);
  }
  #pragma unroll
  for (int t = 1; t < 16; ++t) {
    float4 q0 = X4[2 * t], q1 = X4[2 * t + 1];
    r[0] = __fadd_rn(r[0], __fmul_rn(q0.x, q0.x));
    r[1] = __fadd_rn(r[1], __fmul_rn(q0.y, q0.y));
    r[2] = __fadd_rn(r[2], __fmul_rn(q0.z, q0.z));
    r[3] = __fadd_rn(r[3], __fmul_rn(q0.w, q0.w));
    r[4] = __fadd_rn(r[4], __fmul_rn(q1.x, q1.x));
    r[5] = __fadd_rn(r[5], __fmul_rn(q1.y, q1.y));
    r[6] = __fadd_rn(r[6], __fmul_rn(q1.z, q1.z));
    r[7] = __fadd_rn(r[7], __fmul_rn(q1.w, q1.w));
  }
  float t01 = __fadd_rn(r[0], r[1]), t23 = __fadd_rn(r[2], r[3]);
  float t45 = __fadd_rn(r[4], r[5]), t67 = __fadd_rn(r[6], r[7]);
  xnorm[p] = __fadd_rn(__fadd_rn(t01, t23), __fadd_rn(t45, t67));
}

// ---------------- assignment: 512 threads, 4x8 per-thread tile (higher occupancy) ------
// Same 128pt x 512cl block tile and LDS layout as R20 (passed, 0 conflicts). Each (p,k)
// chain consumes d = dch*64 + dq*4 + {x,y,z,w} strictly ascending — identical arithmetic.
// Smaller acc (4x8=32 regs) -> VGPR <= 128 -> 16 waves/CU tier (2x residency).
__global__ __launch_bounds__(512, 2)
void k_assign_e(const float* __restrict__ X, const float* __restrict__ C,
                const float* __restrict__ cnorm, const float* __restrict__ xnorm,
                int* __restrict__ labels) {
  __shared__ __align__(16) float Xs[128][68];   // [point][dim], 272B row stride
  __shared__ __align__(16) float Cs[128][68];   // [cluster][dim]
  const int tid = threadIdx.x;
  const int tx = tid & 15, ty = tid >> 4;       // tx: 16 cluster-cols, ty: 32 point-rows
  const int row0 = blockIdx.x * 128;
  const float4* X4 = (const float4*)X;
  const float4* C4 = (const float4*)C;

  float xn[4];
  #pragma unroll
  for (int r = 0; r < 4; ++r) xn[r] = xnorm[row0 + ty + 32 * r];

  float best[4];
  int bestk[4], fnan[4];
  #pragma unroll
  for (int r = 0; r < 4; ++r) { best[r] = 0.0f; bestk[r] = -1; fnan[r] = 0x7fffffff; }

  for (int kc = 0; kc < 4; ++kc) {
    float acc[4][8];
    #pragma unroll
    for (int r = 0; r < 4; ++r)
      #pragma unroll
      for (int j = 0; j < 8; ++j) acc[r][j] = 0.0f;

    for (int dch = 0; dch < 2; ++dch) {        // two 64-dim chunks
      __syncthreads();
      #pragma unroll
      for (int i = 0; i < 4; ++i) {            // stage 128 pts + 128 clusters x 64 dims
        int idx = tid + 512 * i, p = idx >> 4, q = idx & 15;
        *(float4*)&Xs[p][q * 4] = X4[(size_t)(row0 + p) * 32 + dch * 16 + q];
        *(float4*)&Cs[p][q * 4] = C4[(size_t)(kc * 128 + p) * 32 + dch * 16 + q];
      }
      __syncthreads();
      for (int dq = 0; dq < 16; ++dq) {        // 4 dims per iteration, d ascending
        float4 xv[4], cv[8];
        #pragma unroll
        for (int r = 0; r < 4; ++r) xv[r] = *(const float4*)&Xs[ty + 32 * r][dq * 4];
        #pragma unroll
        for (int j = 0; j < 8; ++j) cv[j] = *(const float4*)&Cs[j * 16 + tx][dq * 4];
        #pragma unroll
        for (int r = 0; r < 4; ++r)
          #pragma unroll
          for (int j = 0; j < 8; ++j) {
            acc[r][j] = __fmaf_rn(xv[r].x, cv[j].x, acc[r][j]);
            acc[r][j] = __fmaf_rn(xv[r].y, cv[j].y, acc[r][j]);
            acc[r][j] = __fmaf_rn(xv[r].z, cv[j].z, acc[r][j]);
            acc[r][j] = __fmaf_rn(xv[r].w, cv[j].w, acc[r][j]);
          }
      }
    }
    // epilogue for this kc: per-thread k-ascending argmin with np semantics
    #pragma unroll
    for (int r = 0; r < 4; ++r) {
      #pragma unroll
      for (int j = 0; j < 8; ++j) {
        int k = kc * 128 + j * 16 + tx;
        float s = __fadd_rn(__fsub_rn(xn[r], __fmul_rn(2.0f, acc[r][j])), cnorm[k]);
        if (isnan_bits32(s)) {
          if (k < fnan[r]) fnan[r] = k;
        } else if (bestk[r] < 0 || s < best[r]) {
          best[r] = s; bestk[r] = k;
        }
      }
    }
  }
  // cross-lane reduce over the 16 tx lanes (masks 1,2,4,8 stay within ty groups)
  #pragma unroll
  for (int r = 0; r < 4; ++r) {
    float b = best[r]; int bk = bestk[r]; int fn = fnan[r];
    #pragma unroll
    for (int m = 8; m; m >>= 1) {
      float ob = __shfl_xor(b, m, 64);
      int obk = __shfl_xor(bk, m, 64);
      int ofn = __shfl_xor(fn, m, 64);
      if (ofn < fn) fn = ofn;
      bool take = (obk >= 0) && (bk < 0 || ob < b || (ob == b && obk < bk));
      if (take) { b = ob; bk = obk; }
    }
    if (tx == 0) labels[row0 + ty + 32 * r] = (fn != 0x7fffffff) ? fn : bk;
  }
}

// ======== deterministic counting-sort update (unchanged from passing R8-R20) ========

__global__ void k_hist(const int* __restrict__ labels, int* __restrict__ counts) {
  __shared__ int hist[KCL];
  int c = blockIdx.x, t = threadIdx.x;
  hist[t] = 0; hist[t + 256] = 0;
  __syncthreads();
  int lab = labels[c * CHS + t];
  atomicAdd(&hist[lab], 1);
  __syncthreads();
  counts[(size_t)t * NCH + c] = hist[t];
  counts[(size_t)(t + 256) * NCH + c] = hist[t + 256];
}

__global__ void k_scan_chunks(const int* __restrict__ counts, int* __restrict__ cbase,
                              int* __restrict__ total) {
  __shared__ int s[NCH];
  int k = blockIdx.x, c = threadIdx.x;
  int v = counts[(size_t)k * NCH + c];
  s[c] = v;
  __syncthreads();
  for (int off = 1; off < NCH; off <<= 1) {
    int t = (c >= off) ? s[c - off] : 0;
    __syncthreads();
    s[c] += t;
    __syncthreads();
  }
  cbase[(size_t)k * NCH + c] = s[c] - v;
  if (c == NCH - 1) total[k] = s[c];
}

__global__ void k_scan_k(const int* __restrict__ total, int* __restrict__ offset) {
  __shared__ int s[KCL];
  int c = threadIdx.x;
  int v = total[c];
  s[c] = v;
  __syncthreads();
  for (int off = 1; off < KCL; off <<= 1) {
    int t = (c >= off) ? s[c - off] : 0;
    __syncthreads();
    s[c] += t;
    __syncthreads();
  }
  offset[c] = s[c] - v;
}

__global__ void k_scatter(const int* __restrict__ labels, const int* __restrict__ cbase,
                          const int* __restrict__ offset, int* __restrict__ list) {
  __shared__ int lab[CHS];
  int c = blockIdx.x, t = threadIdx.x;
  int L = labels[c * CHS + t];
  lab[t] = L;
  __syncthreads();
  int rank = 0;
  for (int j = 0; j < t; ++j) rank += (lab[j] == L);
  list[offset[L] + cbase[(size_t)L * NCH + c] + rank] = c * CHS + t;
}

__global__ void k_sum(const float* __restrict__ X, const int* __restrict__ list,
                      const int* __restrict__ offset, const int* __restrict__ total,
                      float* __restrict__ C, float* __restrict__ cnorm) {
  int k = blockIdx.x, d = threadIdx.x;
  int n = total[k], off = offset[k];
  float acc = 0.0f;
  int t = 0;
  for (; t + 4 <= n; t += 4) {
    int i0 = list[off + t + 0], i1 = list[off + t + 1];
    int i2 = list[off + t + 2], i3 = list[off + t + 3];
    float x0 = X[(size_t)i0 * DI + d], x1 = X[(size_t)i1 * DI + d];
    float x2 = X[(size_t)i2 * DI + d], x3 = X[(size_t)i3 * DI + d];
    acc = __fadd_rn(acc, x0); acc = __fadd_rn(acc, x1);
    acc = __fadd_rn(acc, x2); acc = __fadd_rn(acc, x3);
  }
  for (; t < n; ++t) {
    int i = list[off + t];
    acc = __fadd_rn(acc, X[(size_t)i * DI + d]);
  }
  float cv = (n == 0) ? __uint_as_float(0x7FC00000u) : __fdiv_rn(acc, (float)n);
  C[(size_t)k * DI + d] = cv;
  __shared__ float row[DI];
  row[d] = cv;
  __syncthreads();
  if (d == 0) cnorm[k] = np_pairwise128_sq(row);
}

extern "C" void kernel_launch(void* const* d_in, const int* in_sizes, int n_in,
                              void* d_out, int out_size, void* d_ws, size_t ws_size,
                              hipStream_t stream) {
  (void)in_sizes; (void)n_in; (void)out_size; (void)ws_size;
  const float* X = (const float*)d_in[0];
  int* out = (int*)d_out;
  char* ws = (char*)d_ws;
  float* C      = (float*)(ws);                              // 256 KB
  float* cnorm  = (float*)(ws + 262144);                     // 2 KB
  float* xnorm  = (float*)(ws + 264192);                     // 1 MB
  int*   counts = (int*)(ws + 264192 + 1048576);             // 2 MB
  int*   cbase  = (int*)(ws + 264192 + 1048576 + 2097152);   // 2 MB
  int*   total  = (int*)(ws + 264192 + 1048576 + 2 * 2097152);         // 2 KB
  int*   offset = (int*)(ws + 264192 + 1048576 + 2 * 2097152 + 2048);  // 2 KB
  int*   list   = (int*)(ws + 264192 + 1048576 + 2 * 2097152 + 4096);  // 1 MB

  k_init<<<KCL, DI, 0, stream>>>(X, C, cnorm);
  k_xnorm<<<NP / 256, 256, 0, stream>>>(X, xnorm);
  for (int t = 0; t < NIT; ++t) {
    k_assign_e<<<NP / 128, 512, 0, stream>>>(X, C, cnorm, xnorm, out);
    if (t < NIT - 1) {
      k_hist<<<NCH, CHS, 0, stream>>>(out, counts);
      k_scan_chunks<<<KCL, NCH, 0, stream>>>(counts, cbase, total);
      k_scan_k<<<1, KCL, 0, stream>>>(total, offset);
      k_scatter<<<NCH, CHS, 0, stream>>>(out, cbase, offset, list);
      k_sum<<<KCL, DI, 0, stream>>>(X, list, offset, total, C, cnorm);
    }
  }
}

// Round 22
// 5639.496 us; speedup vs baseline: 1.1123x; 1.1123x over previous
//
#include <hip/hip_runtime.h>

#define NP 262144
#define DI 128
#define KCL 512
#define NIT 10
#define NCH 1024      // chunks for the counting sort
#define CHS 256       // points per chunk (NCH*CHS == NP)

// Fast-math-immune fp32 NaN test.
__device__ __forceinline__ bool isnan_bits32(float x) {
  unsigned b = __float_as_uint(x);
  return (b & 0x7FFFFFFFu) > 0x7F800000u;
}

// numpy pairwise_sum of v[i]*v[i] for n=128 (numpy's 8-accumulator unrolled path).
__device__ __forceinline__ float np_pairwise128_sq(const float* v) {
  float r[8];
  #pragma unroll
  for (int j = 0; j < 8; ++j) r[j] = __fmul_rn(v[j], v[j]);
  #pragma unroll
  for (int t = 1; t < 16; ++t)
    #pragma unroll
    for (int j = 0; j < 8; ++j)
      r[j] = __fadd_rn(r[j], __fmul_rn(v[8 * t + j], v[8 * t + j]));
  float t01 = __fadd_rn(r[0], r[1]), t23 = __fadd_rn(r[2], r[3]);
  float t45 = __fadd_rn(r[4], r[5]), t67 = __fadd_rn(r[6], r[7]);
  return __fadd_rn(__fadd_rn(t01, t23), __fadd_rn(t45, t67));
}

// ---------------- init: C0 = X[:512]; cnorm[k] = np-pairwise of c*c ----------------
__global__ void k_init(const float* __restrict__ X, float* __restrict__ C,
                       float* __restrict__ cnorm) {
  int k = blockIdx.x, d = threadIdx.x;
  float v = X[(size_t)k * DI + d];
  C[(size_t)k * DI + d] = v;
  __shared__ float row[DI];
  row[d] = v;
  __syncthreads();
  if (d == 0) cnorm[k] = np_pairwise128_sq(row);
}

// ---------------- xnorm: once per run (X constant). Streaming 8-acc pairwise. ----------
__global__ void k_xnorm(const float* __restrict__ X, float* __restrict__ xnorm) {
  const int p = blockIdx.x * 256 + threadIdx.x;
  const float4* X4 = (const float4*)X + (size_t)p * 32;
  float r[8];
  {
    float4 q0 = X4[0], q1 = X4[1];
    r[0] = __fmul_rn(q0.x, q0.x); r[1] = __fmul_rn(q0.y, q0.y);
    r[2] = __fmul_rn(q0.z, q0.z); r[3] = __fmul_rn(q0.w, q0.w);
    r[4] = __fmul_rn(q1.x, q1.x); r[5] = __fmul_rn(q1.y, q1.y);
    r[6] = __fmul_rn(q1.z, q1.z); r[7] = __fmul_rn(q1.w, q1.w);
  }
  #pragma unroll
  for (int t = 1; t < 16; ++t) {
    float4 q0 = X4[2 * t], q1 = X4[2 * t + 1];
    r[0] = __fadd_rn(r[0], __fmul_rn(q0.x, q0.x));
    r[1] = __fadd_rn(r[1], __fmul_rn(q0.y, q0.y));
    r[2] = __fadd_rn(r[2], __fmul_rn(q0.z, q0.z));
    r[3] = __fadd_rn(r[3], __fmul_rn(q0.w, q0.w));
    r[4] = __fadd_rn(r[4], __fmul_rn(q1.x, q1.x));
    r[5] = __fadd_rn(r[5], __fmul_rn(q1.y, q1.y));
    r[6] = __fadd_rn(r[6], __fmul_rn(q1.z, q1.z));
    r[7] = __fadd_rn(r[7], __fmul_rn(q1.w, q1.w));
  }
  float t01 = __fadd_rn(r[0], r[1]), t23 = __fadd_rn(r[2], r[3]);
  float t45 = __fadd_rn(r[4], r[5]), t67 = __fadd_rn(r[6], r[7]);
  xnorm[p] = __fadd_rn(__fadd_rn(t01, t23), __fadd_rn(t45, t67));
}

// ---------------- assignment: R20 verbatim (best measured: 6082 us total) ----------
// [point][dim] padded LDS, b128 reads, 64-dim chunks, 8x8 tile, (256,2).
// Per-(p,k) chain consumes d ascending — bit-identical to R8. Zero bank conflicts.
__global__ __launch_bounds__(256, 2)
void k_assign_q(const float* __restrict__ X, const float* __restrict__ C,
                const float* __restrict__ cnorm, const float* __restrict__ xnorm,
                int* __restrict__ labels) {
  __shared__ __align__(16) float Xs[128][68];   // [point][dim], 272B row stride
  __shared__ __align__(16) float Cs[128][68];   // [cluster][dim]
  const int tid = threadIdx.x;
  const int tx = tid & 15, ty = tid >> 4;
  const int row0 = blockIdx.x * 128;
  const float4* X4 = (const float4*)X;
  const float4* C4 = (const float4*)C;

  float xn[8];
  #pragma unroll
  for (int r = 0; r < 8; ++r) xn[r] = xnorm[row0 + ty + 16 * r];

  float best[8];
  int bestk[8], fnan[8];
  #pragma unroll
  for (int r = 0; r < 8; ++r) { best[r] = 0.0f; bestk[r] = -1; fnan[r] = 0x7fffffff; }

  for (int kc = 0; kc < 4; ++kc) {
    float acc[8][8];
    #pragma unroll
    for (int r = 0; r < 8; ++r)
      #pragma unroll
      for (int j = 0; j < 8; ++j) acc[r][j] = 0.0f;

    for (int dch = 0; dch < 2; ++dch) {        // two 64-dim chunks
      __syncthreads();
      #pragma unroll
      for (int i = 0; i < 8; ++i) {            // stage 128 pts + 128 clusters x 64 dims
        int idx = tid + 256 * i, p = idx >> 4, q = idx & 15;
        *(float4*)&Xs[p][q * 4] = X4[(size_t)(row0 + p) * 32 + dch * 16 + q];
        *(float4*)&Cs[p][q * 4] = C4[(size_t)(kc * 128 + p) * 32 + dch * 16 + q];
      }
      __syncthreads();
      for (int dq = 0; dq < 16; ++dq) {        // 4 dims per iteration, d ascending
        float4 xv[8], cv[8];
        #pragma unroll
        for (int r = 0; r < 8; ++r) xv[r] = *(const float4*)&Xs[ty + 16 * r][dq * 4];
        #pragma unroll
        for (int j = 0; j < 8; ++j) cv[j] = *(const float4*)&Cs[j * 16 + tx][dq * 4];
        #pragma unroll
        for (int r = 0; r < 8; ++r)
          #pragma unroll
          for (int j = 0; j < 8; ++j) {
            acc[r][j] = __fmaf_rn(xv[r].x, cv[j].x, acc[r][j]);
            acc[r][j] = __fmaf_rn(xv[r].y, cv[j].y, acc[r][j]);
            acc[r][j] = __fmaf_rn(xv[r].z, cv[j].z, acc[r][j]);
            acc[r][j] = __fmaf_rn(xv[r].w, cv[j].w, acc[r][j]);
          }
      }
    }
    // epilogue for this kc: per-thread k-ascending argmin with np semantics
    #pragma unroll
    for (int r = 0; r < 8; ++r) {
      #pragma unroll
      for (int j = 0; j < 8; ++j) {
        int k = kc * 128 + j * 16 + tx;
        float s = __fadd_rn(__fsub_rn(xn[r], __fmul_rn(2.0f, acc[r][j])), cnorm[k]);
        if (isnan_bits32(s)) {
          if (k < fnan[r]) fnan[r] = k;
        } else if (bestk[r] < 0 || s < best[r]) {
          best[r] = s; bestk[r] = k;
        }
      }
    }
  }
  // cross-lane reduce over the 16 tx lanes (masks 1,2,4,8 stay within ty groups)
  #pragma unroll
  for (int r = 0; r < 8; ++r) {
    float b = best[r]; int bk = bestk[r]; int fn = fnan[r];
    #pragma unroll
    for (int m = 8; m; m >>= 1) {
      float ob = __shfl_xor(b, m, 64);
      int obk = __shfl_xor(bk, m, 64);
      int ofn = __shfl_xor(fn, m, 64);
      if (ofn < fn) fn = ofn;
      bool take = (obk >= 0) && (bk < 0 || ob < b || (ob == b && obk < bk));
      if (take) { b = ob; bk = obk; }
    }
    if (tx == 0) labels[row0 + ty + 16 * r] = (fn != 0x7fffffff) ? fn : bk;
  }
}

// ======== deterministic counting-sort update (sort kernels unchanged; k_sum ILP x8) ========

__global__ void k_hist(const int* __restrict__ labels, int* __restrict__ counts) {
  __shared__ int hist[KCL];
  int c = blockIdx.x, t = threadIdx.x;
  hist[t] = 0; hist[t + 256] = 0;
  __syncthreads();
  int lab = labels[c * CHS + t];
  atomicAdd(&hist[lab], 1);
  __syncthreads();
  counts[(size_t)t * NCH + c] = hist[t];
  counts[(size_t)(t + 256) * NCH + c] = hist[t + 256];
}

__global__ void k_scan_chunks(const int* __restrict__ counts, int* __restrict__ cbase,
                              int* __restrict__ total) {
  __shared__ int s[NCH];
  int k = blockIdx.x, c = threadIdx.x;
  int v = counts[(size_t)k * NCH + c];
  s[c] = v;
  __syncthreads();
  for (int off = 1; off < NCH; off <<= 1) {
    int t = (c >= off) ? s[c - off] : 0;
    __syncthreads();
    s[c] += t;
    __syncthreads();
  }
  cbase[(size_t)k * NCH + c] = s[c] - v;
  if (c == NCH - 1) total[k] = s[c];
}

__global__ void k_scan_k(const int* __restrict__ total, int* __restrict__ offset) {
  __shared__ int s[KCL];
  int c = threadIdx.x;
  int v = total[c];
  s[c] = v;
  __syncthreads();
  for (int off = 1; off < KCL; off <<= 1) {
    int t = (c >= off) ? s[c - off] : 0;
    __syncthreads();
    s[c] += t;
    __syncthreads();
  }
  offset[c] = s[c] - v;
}

__global__ void k_scatter(const int* __restrict__ labels, const int* __restrict__ cbase,
                          const int* __restrict__ offset, int* __restrict__ list) {
  __shared__ int lab[CHS];
  int c = blockIdx.x, t = threadIdx.x;
  int L = labels[c * CHS + t];
  lab[t] = L;
  __syncthreads();
  int rank = 0;
  for (int j = 0; j < t; ++j) rank += (lab[j] == L);
  list[offset[L] + cbase[(size_t)L * NCH + c] + rank] = c * CHS + t;
}

// k_sum: adds stay strictly i-ascending (bit-exact); loads are order-free -> 8-deep ILP.
__global__ void k_sum(const float* __restrict__ X, const int* __restrict__ list,
                      const int* __restrict__ offset, const int* __restrict__ total,
                      float* __restrict__ C, float* __restrict__ cnorm) {
  int k = blockIdx.x, d = threadIdx.x;
  int n = total[k], off = offset[k];
  float acc = 0.0f;
  int t = 0;
  for (; t + 8 <= n; t += 8) {
    int i0 = list[off + t + 0], i1 = list[off + t + 1];
    int i2 = list[off + t + 2], i3 = list[off + t + 3];
    int i4 = list[off + t + 4], i5 = list[off + t + 5];
    int i6 = list[off + t + 6], i7 = list[off + t + 7];
    float x0 = X[(size_t)i0 * DI + d], x1 = X[(size_t)i1 * DI + d];
    float x2 = X[(size_t)i2 * DI + d], x3 = X[(size_t)i3 * DI + d];
    float x4 = X[(size_t)i4 * DI + d], x5 = X[(size_t)i5 * DI + d];
    float x6 = X[(size_t)i6 * DI + d], x7 = X[(size_t)i7 * DI + d];
    acc = __fadd_rn(acc, x0); acc = __fadd_rn(acc, x1);
    acc = __fadd_rn(acc, x2); acc = __fadd_rn(acc, x3);
    acc = __fadd_rn(acc, x4); acc = __fadd_rn(acc, x5);
    acc = __fadd_rn(acc, x6); acc = __fadd_rn(acc, x7);
  }
  for (; t < n; ++t) {
    int i = list[off + t];
    acc = __fadd_rn(acc, X[(size_t)i * DI + d]);
  }
  float cv = (n == 0) ? __uint_as_float(0x7FC00000u) : __fdiv_rn(acc, (float)n);
  C[(size_t)k * DI + d] = cv;
  __shared__ float row[DI];
  row[d] = cv;
  __syncthreads();
  if (d == 0) cnorm[k] = np_pairwise128_sq(row);
}

extern "C" void kernel_launch(void* const* d_in, const int* in_sizes, int n_in,
                              void* d_out, int out_size, void* d_ws, size_t ws_size,
                              hipStream_t stream) {
  (void)in_sizes; (void)n_in; (void)out_size; (void)ws_size;
  const float* X = (const float*)d_in[0];
  int* out = (int*)d_out;
  char* ws = (char*)d_ws;
  float* C      = (float*)(ws);                              // 256 KB
  float* cnorm  = (float*)(ws + 262144);                     // 2 KB
  float* xnorm  = (float*)(ws + 264192);                     // 1 MB
  int*   counts = (int*)(ws + 264192 + 1048576);             // 2 MB
  int*   cbase  = (int*)(ws + 264192 + 1048576 + 2097152);   // 2 MB
  int*   total  = (int*)(ws + 264192 + 1048576 + 2 * 2097152);         // 2 KB
  int*   offset = (int*)(ws + 264192 + 1048576 + 2 * 2097152 + 2048);  // 2 KB
  int*   list   = (int*)(ws + 264192 + 1048576 + 2 * 2097152 + 4096);  // 1 MB

  k_init<<<KCL, DI, 0, stream>>>(X, C, cnorm);
  k_xnorm<<<NP / 256, 256, 0, stream>>>(X, xnorm);
  for (int t = 0; t < NIT; ++t) {
    k_assign_q<<<NP / 128, 256, 0, stream>>>(X, C, cnorm, xnorm, out);
    if (t < NIT - 1) {
      k_hist<<<NCH, CHS, 0, stream>>>(out, counts);
      k_scan_chunks<<<KCL, NCH, 0, stream>>>(counts, cbase, total);
      k_scan_k<<<1, KCL, 0, stream>>>(total, offset);
      k_scatter<<<NCH, CHS, 0, stream>>>(out, cbase, offset, list);
      k_sum<<<KCL, DI, 0, stream>>>(X, list, offset, total, C, cnorm);
    }
  }
}